// Round 5
// baseline (12.247 us; speedup 1.0000x reference)
//
#include <hip/hip_runtime.h>

// Ricker predation scan, parallel-in-time via contraction warm-up (round 5).
// vs round 4 (10.6 us): phase 2 was LDS-pipe bound (~2.3k cyc/CU of
// ds_read_b128) with 2.94 serial steps per output (WARM32 + CHUNK16).
//  - CHUNK 16 -> 32: 1.97 steps/output (-33% phase-2 LDS reads, exps, FMAs).
//  - BLOCK 64 (1-wave blocks), GRID 512 -> still 2 independent blocks/CU for
//    cross-block phase overlap; __syncthreads is intra-wave (near-free).
//  - Out staging written as ds_write_b128 quads (was 64x b32 per thread).
//  - No scalar edge path: block 0 skips the 8 lead-in quads (slots 0..31 are
//    provably never read: thread 0 has nwarm=0), e2 scalar loads clamp at
//    NSTEPS-1 (avoids 4B OOB past the eps buffer on the last block).

#define T_LEN_C (1 << 20)
#define NSTEPS  (T_LEN_C - 1)
#define CHUNK   32
#define WARM    32
#define SPAN    32
#define BLOCK   64
#define OWNED   (BLOCK * CHUNK)        // 2048
#define GRID    (T_LEN_C / OWNED)      // 512
#define STAGE_N (OWNED + SPAN)         // 2080
#define NQ      (STAGE_N / 4)          // 520 staged quads
#define RQ      (NQ / BLOCK)           // 8 full rounds
#define TAILQ   (NQ - RQ * BLOCK)      // 8 tail quads
#define SLOTS4  (STAGE_N + (STAGE_N >> 5) + 2)
#define PITCH4  (CHUNK / 4 + 1)        // 9 float4 per out-staging row

__device__ __forceinline__ int swz(int L) { return L + (L >> 5); }

__global__ __launch_bounds__(BLOCK) void ricker_kernel(
    const float* __restrict__ Temp,
    const float* __restrict__ params,
    const float* __restrict__ eps,
    float* __restrict__ out)
{
    __shared__ float4 sCE[SLOTS4];                 // {c1,c2,s*e1,s*e2}/element
    __shared__ float4 sX4[BLOCK * PITCH4];
    __shared__ float4 sY4[BLOCK * PITCH4];

    const int tid      = threadIdx.x;
    const int bid      = blockIdx.x;
    const int blk_base = bid * OWNED;
    const int blk_lo   = blk_base - SPAN;          // multiple of 32 (may be -32)

    // params: a1,b1,g1,bx1,cx1, a2,b2,g2,bx2,cx2, sigma
    const float a1  = params[0], b1 = params[1], g1 = params[2];
    const float bx1 = params[3], cx1 = params[4];
    const float a2  = params[5], b2 = params[6], g2 = params[7];
    const float bx2 = params[8], cx2 = params[9];
    const float s   = params[10] * 0.1f;           // sigma * STD

    const float L2E  = 1.4426950408889634f;        // exp -> exp2
    const float A1   = a1 * L2E,  A2   = a2 * L2E;
    const float nAb1 = -A1 * b1,  nAg1 = -A1 * g1;
    const float Abx1 =  A1 * bx1, Acx1 =  A1 * cx1;
    const float nAb2 = -A2 * b2,  nAg2 = -A2 * g2;
    const float Abx2 =  A2 * bx2, Acx2 =  A2 * cx2;

    const float* __restrict__ e1p = eps;           // noise row 0 (16B-aligned)
    const float* __restrict__ e2p = eps + NSTEPS;  // noise row 1 (4B-misaligned)

    // ---- Phase 1: batched global->reg, then coeffs -> LDS ----
    const float4* __restrict__ T4  = reinterpret_cast<const float4*>(Temp) + (blk_lo >> 2);
    const float4* __restrict__ E14 = reinterpret_cast<const float4*>(e1p)  + (blk_lo >> 2);

    float4 t4[RQ + 1], f4[RQ + 1];
    float  e2s[4 * (RQ + 1)];
    #pragma unroll
    for (int r = 0; r <= RQ; ++r) {
        const bool act = (r < RQ) ? !(bid == 0 && r == 0 && tid < (SPAN / 4))
                                  : (tid < TAILQ);
        if (act) {
            const int q = (r < RQ) ? (tid + r * BLOCK) : (RQ * BLOCK + tid);
            t4[r] = T4[q];
            f4[r] = E14[q];
            const int gb = blk_lo + 4 * q;
            #pragma unroll
            for (int j = 0; j < 4; ++j) {
                int g2 = gb + j;                    // e2 row: clamp 4B-OOB tail
                g2 = g2 > NSTEPS - 1 ? NSTEPS - 1 : g2;
                e2s[4 * r + j] = e2p[g2];
            }
        }
    }
    #pragma unroll
    for (int r = 0; r <= RQ; ++r) {
        const bool act = (r < RQ) ? !(bid == 0 && r == 0 && tid < (SPAN / 4))
                                  : (tid < TAILQ);
        if (act) {
            const int q = (r < RQ) ? (tid + r * BLOCK) : (RQ * BLOCK + tid);
            const float tv[4] = {t4[r].x, t4[r].y, t4[r].z, t4[r].w};
            const float ev[4] = {f4[r].x, f4[r].y, f4[r].z, f4[r].w};
            #pragma unroll
            for (int j = 0; j < 4; ++j) {
                const int L = 4 * q + j;
                const float t = tv[j], tq = t * t;
                sCE[swz(L)] = make_float4(
                    fmaf(Acx1, tq, fmaf(Abx1, t, A1)),
                    fmaf(Acx2, tq, fmaf(Abx2, t, A2)),
                    s * ev[j], s * e2s[4 * r + j]);
            }
        }
    }
    __syncthreads();

    // ---- Phase 2: 63 serial steps (32 warm + 31 owned), pre-step staging ----
#define STEP()                                                          \
    do {                                                                \
        const float4 c = sCE[swz(L)]; ++L;                              \
        const float ax = fmaf(nAb1, x, fmaf(nAg1, y, c.x));             \
        const float ay = fmaf(nAb2, y, fmaf(nAg2, x, c.y));             \
        const float xn = fmaf(x, __builtin_amdgcn_exp2f(ax), c.z);      \
        const float yn = fmaf(y, __builtin_amdgcn_exp2f(ay), c.w);      \
        x = xn; y = yn;                                                 \
    } while (0)

    const int base  = blk_base + tid * CHUNK;
    const int nwarm = base < WARM ? base : WARM;   // 0 only for bid0/tid0
    int L = tid * CHUNK + (SPAN - nwarm);
    float x = 1.0f, y = 1.0f;

    #pragma unroll 8
    for (int w = 0; w < nwarm; ++w) STEP();

    // state == x_traj[base] (pre-step). Store 32 pre-step states, 31 computes.
    float4* __restrict__ px = &sX4[tid * PITCH4];
    float4* __restrict__ py = &sY4[tid * PITCH4];
    #pragma unroll
    for (int qh = 0; qh < CHUNK / 4; ++qh) {
        float4 xs, ys;
        xs.x = x; ys.x = y; STEP();
        xs.y = x; ys.y = y; STEP();
        xs.z = x; ys.z = y; STEP();
        xs.w = x; ys.w = y;
        if (qh < CHUNK / 4 - 1) STEP();            // last owned compute skipped
        px[qh] = xs;
        py[qh] = ys;
    }
    __syncthreads();

    // ---- Phase 3: LDS -> aligned float4 coalesced global stores ----
    #pragma unroll
    for (int rr = 0; rr < OWNED / 4 / BLOCK; ++rr) {   // 8 rounds
        const int v   = tid + rr * BLOCK;              // output quad 0..511
        const int row = v >> 3;                        // writer thread
        const int qh  = v & 7;
        const float4 xv = sX4[row * PITCH4 + qh];
        const float4 yv = sY4[row * PITCH4 + qh];
        *reinterpret_cast<float4*>(&out[blk_base + 4 * v])           = xv;
        *reinterpret_cast<float4*>(&out[T_LEN_C + blk_base + 4 * v]) = yv;
    }
#undef STEP
}

extern "C" void kernel_launch(void* const* d_in, const int* in_sizes, int n_in,
                              void* d_out, int out_size, void* d_ws, size_t ws_size,
                              hipStream_t stream)
{
    const float* Temp   = (const float*)d_in[0];
    const float* params = (const float*)d_in[1];
    const float* eps    = (const float*)d_in[2];
    float*       out    = (float*)d_out;

    ricker_kernel<<<GRID, BLOCK, 0, stream>>>(Temp, params, eps, out);
}

// Round 6
// 10.504 us; speedup vs baseline: 1.1660x; 1.1660x over previous
//
#include <hip/hip_runtime.h>

// Ricker predation scan, parallel-in-time via contraction warm-up (round 6).
// Round-5 post-mortem: CHUNK32/BLOCK64 (512 waves total = 2 waves/CU, half
// the SIMDs idle) REGRESSED 10.6->12.2us => the kernel is latency-bound, not
// LDS-throughput-bound. Round 6 goes the other way: many short chains.
//  - CHUNK 8, WARM 16: 23 serial steps/thread (was 47/63).
//  - 131072 threads = 2048 waves = 8 waves/CU (2/SIMD), GRID=1024 -> 4
//    resident blocks/CU for cross-block phase overlap.
//  - Total wave-steps ~= round 4 (same issue load) with 2x latency hiding.
//  - WARM 16 safe: lambda~0.63 => warm error ~2e-4 << 3.9e-3 systematic.

#define T_LEN_C (1 << 20)
#define NSTEPS  (T_LEN_C - 1)
#define CHUNK   8
#define WARM    16
#define SPAN    16
#define BLOCK   128
#define OWNED   (BLOCK * CHUNK)        // 1024
#define GRID    (T_LEN_C / OWNED)      // 1024
#define STAGE_N (OWNED + SPAN)         // 1040
#define NQ      (STAGE_N / 4)          // 260 staged quads
#define RQ      (NQ / BLOCK)           // 2 full rounds
#define TAILQ   (NQ - RQ * BLOCK)      // 4 tail quads
#define SLOTS4  (STAGE_N + (STAGE_N >> 5) + 2)
#define PITCH4  (CHUNK / 4 + 1)        // 3 float4 per out-staging row

__device__ __forceinline__ int swz(int L) { return L + (L >> 5); }

__global__ __launch_bounds__(BLOCK) void ricker_kernel(
    const float* __restrict__ Temp,
    const float* __restrict__ params,
    const float* __restrict__ eps,
    float* __restrict__ out)
{
    __shared__ float4 sCE[SLOTS4];                 // {c1,c2,s*e1,s*e2}/element
    __shared__ float4 sX4[BLOCK * PITCH4];
    __shared__ float4 sY4[BLOCK * PITCH4];

    const int tid      = threadIdx.x;
    const int bid      = blockIdx.x;
    const int blk_base = bid * OWNED;
    const int blk_lo   = blk_base - SPAN;          // multiple of 16 (may be -16)

    // params: a1,b1,g1,bx1,cx1, a2,b2,g2,bx2,cx2, sigma
    const float a1  = params[0], b1 = params[1], g1 = params[2];
    const float bx1 = params[3], cx1 = params[4];
    const float a2  = params[5], b2 = params[6], g2 = params[7];
    const float bx2 = params[8], cx2 = params[9];
    const float s   = params[10] * 0.1f;           // sigma * STD

    const float L2E  = 1.4426950408889634f;        // exp -> exp2
    const float A1   = a1 * L2E,  A2   = a2 * L2E;
    const float nAb1 = -A1 * b1,  nAg1 = -A1 * g1;
    const float Abx1 =  A1 * bx1, Acx1 =  A1 * cx1;
    const float nAb2 = -A2 * b2,  nAg2 = -A2 * g2;
    const float Abx2 =  A2 * bx2, Acx2 =  A2 * cx2;

    const float* __restrict__ e1p = eps;           // noise row 0 (16B-aligned)
    const float* __restrict__ e2p = eps + NSTEPS;  // noise row 1 (4B-misaligned)

    // ---- Phase 1: batched global->reg, then coeffs -> LDS ----
    const float4* __restrict__ T4  = reinterpret_cast<const float4*>(Temp) + (blk_lo >> 2);
    const float4* __restrict__ E14 = reinterpret_cast<const float4*>(e1p)  + (blk_lo >> 2);

    float4 t4[RQ + 1], f4[RQ + 1];
    float  e2s[4 * (RQ + 1)];
    #pragma unroll
    for (int r = 0; r <= RQ; ++r) {
        const bool act = (r < RQ) ? !(bid == 0 && r == 0 && tid < (SPAN / 4))
                                  : (tid < TAILQ);
        if (act) {
            const int q = (r < RQ) ? (tid + r * BLOCK) : (RQ * BLOCK + tid);
            t4[r] = T4[q];
            f4[r] = E14[q];
            const int gb = blk_lo + 4 * q;
            #pragma unroll
            for (int j = 0; j < 4; ++j) {
                int g2 = gb + j;                    // e2 row: clamp 4B-OOB tail
                g2 = g2 > NSTEPS - 1 ? NSTEPS - 1 : g2;
                e2s[4 * r + j] = e2p[g2];
            }
        }
    }
    #pragma unroll
    for (int r = 0; r <= RQ; ++r) {
        const bool act = (r < RQ) ? !(bid == 0 && r == 0 && tid < (SPAN / 4))
                                  : (tid < TAILQ);
        if (act) {
            const int q = (r < RQ) ? (tid + r * BLOCK) : (RQ * BLOCK + tid);
            const float tv[4] = {t4[r].x, t4[r].y, t4[r].z, t4[r].w};
            const float ev[4] = {f4[r].x, f4[r].y, f4[r].z, f4[r].w};
            #pragma unroll
            for (int j = 0; j < 4; ++j) {
                const int L = 4 * q + j;
                const float t = tv[j], tq = t * t;
                sCE[swz(L)] = make_float4(
                    fmaf(Acx1, tq, fmaf(Abx1, t, A1)),
                    fmaf(Acx2, tq, fmaf(Abx2, t, A2)),
                    s * ev[j], s * e2s[4 * r + j]);
            }
        }
    }
    __syncthreads();

    // ---- Phase 2: 23 serial steps (16 warm + 7 owned), pre-step staging ----
#define STEP()                                                          \
    do {                                                                \
        const float4 c = sCE[swz(L)]; ++L;                              \
        const float ax = fmaf(nAb1, x, fmaf(nAg1, y, c.x));             \
        const float ay = fmaf(nAb2, y, fmaf(nAg2, x, c.y));             \
        const float xn = fmaf(x, __builtin_amdgcn_exp2f(ax), c.z);      \
        const float yn = fmaf(y, __builtin_amdgcn_exp2f(ay), c.w);      \
        x = xn; y = yn;                                                 \
    } while (0)

    float x = 1.0f, y = 1.0f;
    int L;
    if (bid != 0) {
        L = tid * CHUNK;                           // slot of step base-WARM
        #pragma unroll
        for (int w = 0; w < WARM; ++w) STEP();
    } else {
        const int base  = tid * CHUNK;
        const int nwarm = base < WARM ? base : WARM;
        L = tid * CHUNK + (SPAN - nwarm);
        for (int w = 0; w < nwarm; ++w) STEP();
    }

    // state == x_traj[base] (pre-step). Stage 8 pre-step states, 7 computes.
    float4* __restrict__ px = &sX4[tid * PITCH4];
    float4* __restrict__ py = &sY4[tid * PITCH4];
    #pragma unroll
    for (int qh = 0; qh < CHUNK / 4; ++qh) {
        float4 xs, ys;
        xs.x = x; ys.x = y; STEP();
        xs.y = x; ys.y = y; STEP();
        xs.z = x; ys.z = y; STEP();
        xs.w = x; ys.w = y;
        if (qh < CHUNK / 4 - 1) STEP();            // last owned compute skipped
        px[qh] = xs;
        py[qh] = ys;
    }
    __syncthreads();

    // ---- Phase 3: LDS -> aligned float4 coalesced global stores ----
    #pragma unroll
    for (int rr = 0; rr < OWNED / 4 / BLOCK; ++rr) {   // 2 rounds
        const int v   = tid + rr * BLOCK;              // output quad 0..255
        const int row = v >> 1;                        // writer thread
        const int qh  = v & 1;
        const float4 xv = sX4[row * PITCH4 + qh];
        const float4 yv = sY4[row * PITCH4 + qh];
        *reinterpret_cast<float4*>(&out[blk_base + 4 * v])           = xv;
        *reinterpret_cast<float4*>(&out[T_LEN_C + blk_base + 4 * v]) = yv;
    }
#undef STEP
}

extern "C" void kernel_launch(void* const* d_in, const int* in_sizes, int n_in,
                              void* d_out, int out_size, void* d_ws, size_t ws_size,
                              hipStream_t stream)
{
    const float* Temp   = (const float*)d_in[0];
    const float* params = (const float*)d_in[1];
    const float* eps    = (const float*)d_in[2];
    float*       out    = (float*)d_out;

    ricker_kernel<<<GRID, BLOCK, 0, stream>>>(Temp, params, eps, out);
}